// Round 1
// baseline (2904.320 us; speedup 1.0000x reference)
//
#include <hip/hip_runtime.h>

typedef __attribute__((ext_vector_type(8)))  short          bf16x8;
typedef __attribute__((ext_vector_type(16))) float          f32x16;
typedef __attribute__((ext_vector_type(8)))  unsigned int   u32x8;
typedef __attribute__((ext_vector_type(4)))  unsigned short ushort4v;
typedef __attribute__((ext_vector_type(4)))  float          float4v;

#define DEV static __device__ __forceinline__
#define MFMA32(A,B,C) __builtin_amdgcn_mfma_f32_32x32x16_bf16(A,B,C,0,0,0)

// ---- workspace element offsets (unsigned short elements) ----
#define WRES_OFF 0u           // 49 layers * 49 taps * 64*64        = 9,834,496
#define FW_OFF   9834496u     // 49 taps * 64 o * 16 c              =    50,176
#define LW_OFF   9884672u     // 7 * 64 * 64                        =    28,672
#define P1_OFF   9913344u     // 256 * 2048                         =   524,288
#define P2_OFF   10437632u    // 1792 * 256 (padded rows)           =   458,752
#define ACT0_OFF 10896384u    // 1024 * 64p * 64c                   = 4,194,304
#define PV_OFF   15090688u    // 1024 * 32 * 64                     = 2,097,152
#define HID_OFF  17187840u    // 1024 * 256                         =   262,144
// total 17,449,984 ushorts = 34.9 MB

// ---- d_out offsets (floats) ----
#define VAL_OFF 1740800
#define PID_OFF 1741824

// ---- tower LDS map ----
#define SM_Z     57344      // 128B zero row (after 4 * 14336 act buffers)
#define SM_XIN   57472      // 4 * 3584 first-conv input staging
#define SM_BYTES 71808

DEV float bf2f(unsigned short u){ union { unsigned int i; float f; } v; v.i = ((unsigned int)u) << 16; return v.f; }
DEV unsigned short f2bf(float f){
  union { float f; unsigned int i; } v; v.f = f;
  unsigned int x = v.i;
  return (unsigned short)((x + 0x7fffu + ((x >> 16) & 1u)) >> 16);  // RNE
}

// ======================= weight prep =======================
// res_w (7,7,64,64,7,7) f32  ->  wres[L][t][o][c] bf16
__global__ void prep_res_k(const float* __restrict__ res_w, unsigned short* __restrict__ ws){
  __shared__ float buf[3136];
  int bx = blockIdx.x;             // L*64 + o
  int L = bx >> 6, o = bx & 63;
  const float* src = res_w + (size_t)bx * 3136;   // (o fixed): [c][dy][dx] contiguous
  for (int e = threadIdx.x; e < 3136; e += 256) buf[e] = src[e];
  __syncthreads();
  unsigned short* dst = ws + WRES_OFF;
  for (int e = threadIdx.x; e < 3136; e += 256){
    int t = e >> 6, c = e & 63;
    dst[(size_t)(L*49 + t)*4096 + o*64 + c] = f2bf(buf[c*49 + t]);
  }
}

// first_w (63,12,7,7) -> fw[t][o(64)][c(16)] ; last_w cast ; pfc1 cast ; pfc2 cast+pad
__global__ void prep_misc_k(const float* __restrict__ first_w, const float* __restrict__ last_w,
                            const float* __restrict__ pfc1_w, const float* __restrict__ pfc2_w,
                            unsigned short* __restrict__ ws){
  const int n_fw = 49*1024, n_lw = 28672, n_p1 = 524288, n_p2 = 458752;
  const int total = n_fw + n_lw + n_p1 + n_p2;
  for (int d = blockIdx.x*256 + threadIdx.x; d < total; d += gridDim.x*256){
    if (d < n_fw){
      int t = d >> 10, r = d & 1023, o = r >> 4, c = r & 15;
      float v = (o < 63 && c < 12) ? first_w[(o*12 + c)*49 + t] : 0.f;
      ws[FW_OFF + d] = f2bf(v);
    } else if (d < n_fw + n_lw){
      int e = d - n_fw; ws[LW_OFF + e] = f2bf(last_w[e]);
    } else if (d < n_fw + n_lw + n_p1){
      int e = d - n_fw - n_lw; ws[P1_OFF + e] = f2bf(pfc1_w[e]);
    } else {
      int e = d - n_fw - n_lw - n_p1;
      int row = e >> 8, k = e & 255;
      ws[P2_OFF + e] = f2bf(row < 1700 ? pfc2_w[row*256 + k] : 0.f);
    }
  }
}

// ======================= tower =======================
DEV int baddr(int q, bool valid, int imgbase, int hi){
  int sz = (q & 7) << 4;
  int a = (q << 7) + ((imgbase + hi*16) ^ sz);
  return valid ? a : (SM_Z + hi*16);
}

DEV void conv64(unsigned char* smp, const unsigned short* wt,
                f32x16& A00, f32x16& A01, f32x16& A10, f32x16& A11,
                int qb0, int qb1, int y0, int y1, int imgbase, int hi, int col){
  for (int dy = 0; dy < 7; ++dy){
    bool v0 = (unsigned)(y0 + dy - 3) < 8u;
    bool v1 = (unsigned)(y1 + dy - 3) < 8u;
    int tq = (dy-3)*14;
    for (int dx = 0; dx < 7; ++dx){
      __builtin_amdgcn_s_barrier();     // scheduling lockstep only (no data exchange)
      const unsigned short* wtt = wt + (dy*7 + dx)*4096;
      bf16x8 a0k[4], a1k[4];
      #pragma unroll
      for (int ks = 0; ks < 4; ++ks){
        a0k[ks] = *(const bf16x8*)(wtt + col*64      + ks*16 + hi*8);
        a1k[ks] = *(const bf16x8*)(wtt + (32+col)*64 + ks*16 + hi*8);
      }
      int b0 = baddr(qb0 + tq + dx, v0, imgbase, hi);
      int b1 = baddr(qb1 + tq + dx, v1, imgbase, hi);
      #pragma unroll
      for (int ks = 0; ks < 4; ++ks){
        bf16x8 bf0 = *(const bf16x8*)(smp + (b0 ^ (ks << 5)));
        bf16x8 bf1 = *(const bf16x8*)(smp + (b1 ^ (ks << 5)));
        A00 = MFMA32(a0k[ks], bf0, A00);
        A01 = MFMA32(a0k[ks], bf1, A01);
        A10 = MFMA32(a1k[ks], bf0, A10);
        A11 = MFMA32(a1k[ks], bf1, A11);
      }
    }
  }
}

DEV void conv_epi(const f32x16& acc, int mt, int qb, int imgbase, int hi,
                  unsigned char* smp, const float* sp, const float* bp){
  int qw = qb + 3; int swzw = (qw & 7) << 4; int rowb = imgbase + (qw << 7);
  #pragma unroll
  for (int rg = 0; rg < 4; ++rg){
    int o0 = mt*32 + rg*8 + hi*4;
    unsigned short bb[4];
    #pragma unroll
    for (int e = 0; e < 4; ++e){
      float v = sp[o0+e]*acc[rg*4+e] + bp[o0+e];
      v = v > 0.f ? v : 0.f;
      bb[e] = f2bf(v);
    }
    int ob = mt*64 + rg*16 + hi*8;
    *(ushort4v*)(smp + rowb + (ob ^ swzw)) = ushort4v{bb[0],bb[1],bb[2],bb[3]};
  }
}

DEV void res_epi(const f32x16& acc, u32x8& res, int mt, int qb, int imgbase, int hi,
                 unsigned char* smp, const float* lsp, const float* lbp){
  int qw = qb + 3; int swzw = (qw & 7) << 4; int rowb = imgbase + (qw << 7);
  #pragma unroll
  for (int rg = 0; rg < 4; ++rg){
    int o0 = mt*32 + rg*8 + hi*4;
    unsigned short bb[4];
    #pragma unroll
    for (int e = 0; e < 4; ++e){
      unsigned pr = res[rg*2 + (e>>1)];
      float rv = bf2f((unsigned short)((e & 1) ? (pr >> 16) : (pr & 0xffffu)));
      float v = lsp[o0+e]*acc[rg*4+e] + lbp[o0+e] + rv;
      v = v > 0.f ? v : 0.f;
      bb[e] = f2bf(v);
    }
    res[rg*2]   = (unsigned)bb[0] | ((unsigned)bb[1] << 16);
    res[rg*2+1] = (unsigned)bb[2] | ((unsigned)bb[3] << 16);
    int ob = mt*64 + rg*16 + hi*8;
    *(ushort4v*)(smp + rowb + (ob ^ swzw)) = ushort4v{bb[0],bb[1],bb[2],bb[3]};
  }
}

DEV void first_epi(const f32x16& acc, u32x8& res, int mt, int qb, int p, float idsv,
                   int img, int imgbase, int hi, unsigned char* smp,
                   const float* fsp, const float* fbp, unsigned short* act0){
  int qw = qb + 3; int swzw = (qw & 7) << 4; int rowb = imgbase + (qw << 7);
  #pragma unroll
  for (int rg = 0; rg < 4; ++rg){
    int o0 = mt*32 + rg*8 + hi*4;
    unsigned short bb[4];
    #pragma unroll
    for (int e = 0; e < 4; ++e){
      int o = o0 + e;
      int oc = o < 63 ? o : 62;          // avoid OOB load of 63-entry arrays
      float v = fsp[oc]*acc[rg*4+e] + fbp[oc];
      v = v > 0.f ? v : 0.f;
      if (o == 63) v = idsv;             // ids channel, no bn/relu
      bb[e] = f2bf(v);
    }
    res[rg*2]   = (unsigned)bb[0] | ((unsigned)bb[1] << 16);
    res[rg*2+1] = (unsigned)bb[2] | ((unsigned)bb[3] << 16);
    int ob = mt*64 + rg*16 + hi*8;
    *(ushort4v*)(smp + rowb + (ob ^ swzw)) = ushort4v{bb[0],bb[1],bb[2],bb[3]};
    *(ushort4v*)(act0 + (size_t)img*4096 + p*64 + o0) = ushort4v{bb[0],bb[1],bb[2],bb[3]};
  }
}

__global__ __launch_bounds__(256, 2) void tower_k(
    const float* __restrict__ x,
    const float* __restrict__ first_s, const float* __restrict__ first_b,
    const float* __restrict__ res_s,   const float* __restrict__ res_b,
    const float* __restrict__ last_s,  const float* __restrict__ last_b,
    const float* __restrict__ vconv_w, const float* __restrict__ v_s, const float* __restrict__ v_b,
    const float* __restrict__ vfc1_w,  const float* __restrict__ vfc1_b,
    const float* __restrict__ vfc2_w,  const float* __restrict__ vfc2_b,
    const unsigned short* ws_r, unsigned short* act0, float* value_out)
{
  __shared__ unsigned char sm[SM_BYTES];
  int tid = threadIdx.x, lane = tid & 63, wave = tid >> 6;
  int img = blockIdx.x * 4 + wave;

  for (int i = tid*16; i < SM_BYTES; i += 256*16) *(float4v*)(sm + i) = float4v{0,0,0,0};
  __syncthreads();

  int col = lane & 31, hi = lane >> 5;
  int imgbase = wave * 14336;
  int xinbase = SM_XIN + wave * 3584;

  int p0 = col, p1c = 32 + col;
  int y0 = p0 >> 3, y1 = p1c >> 3;
  int qb0 = y0*14 + (p0 & 7), qb1 = y1*14 + (p1c & 7);

  // ---- stage x into padded xin (bf16), channels 0..11 ----
  const float* xim = x + (size_t)img * 832;
  {
    int q = (lane >> 3)*14 + (lane & 7) + 3;
    for (int c = 0; c < 12; ++c){
      *(unsigned short*)(sm + xinbase + q*32 + c*2) = f2bf(xim[c*64 + lane]);
    }
  }
  float ids0 = xim[768 + p0];
  float ids1 = xim[768 + p1c];

  // ---- first conv (K=16: 12 real + 4 zero channels) ----
  f32x16 f00 = {}, f01 = {}, f10 = {}, f11 = {};
  const unsigned short* fw = ws_r + FW_OFF;
  for (int dy = 0; dy < 7; ++dy){
    bool v0 = (unsigned)(y0 + dy - 3) < 8u;
    bool v1 = (unsigned)(y1 + dy - 3) < 8u;
    int tq = (dy-3)*14;
    for (int dx = 0; dx < 7; ++dx){
      int t = dy*7 + dx;
      bf16x8 a0 = *(const bf16x8*)(fw + t*1024 + col*16      + hi*8);
      bf16x8 a1 = *(const bf16x8*)(fw + t*1024 + (32+col)*16 + hi*8);
      int q0 = qb0 + tq + dx, q1 = qb1 + tq + dx;
      int b0a = v0 ? (xinbase + (q0 << 5) + hi*16) : (SM_Z + hi*16);
      int b1a = v1 ? (xinbase + (q1 << 5) + hi*16) : (SM_Z + hi*16);
      bf16x8 bb0 = *(const bf16x8*)(sm + b0a);
      bf16x8 bb1 = *(const bf16x8*)(sm + b1a);
      f00 = MFMA32(a0, bb0, f00);
      f01 = MFMA32(a0, bb1, f01);
      f10 = MFMA32(a1, bb0, f10);
      f11 = MFMA32(a1, bb1, f11);
    }
  }
  u32x8 res00, res01, res10, res11;
  first_epi(f00, res00, 0, qb0, p0,  ids0, img, imgbase, hi, sm, first_s, first_b, act0);
  first_epi(f01, res01, 0, qb1, p1c, ids1, img, imgbase, hi, sm, first_s, first_b, act0);
  first_epi(f10, res10, 1, qb0, p0,  ids0, img, imgbase, hi, sm, first_s, first_b, act0);
  first_epi(f11, res11, 1, qb1, p1c, ids1, img, imgbase, hi, sm, first_s, first_b, act0);

  // ---- residual tower ----
  for (int st = 0; st < 7; ++st){
    for (int j = 0; j < 7; ++j){
      int L = st*7 + j;
      const unsigned short* wt = ws_r + WRES_OFF + (size_t)L*200704u;
      f32x16 c00 = {}, c01 = {}, c10 = {}, c11 = {};
      conv64(sm, wt, c00, c01, c10, c11, qb0, qb1, y0, y1, imgbase, hi, col);
      const float* sp = res_s + L*64;
      const float* bp = res_b + L*64;
      conv_epi(c00, 0, qb0, imgbase, hi, sm, sp, bp);
      conv_epi(c01, 0, qb1, imgbase, hi, sm, sp, bp);
      conv_epi(c10, 1, qb0, imgbase, hi, sm, sp, bp);
      conv_epi(c11, 1, qb1, imgbase, hi, sm, sp, bp);
    }
    // 1x1 (last_w) + bn + residual + relu
    const unsigned short* lw = ws_r + LW_OFF + st*4096;
    const float* lsp = last_s + st*64;
    const float* lbp = last_b + st*64;
    f32x16 c00 = {}, c01 = {}, c10 = {}, c11 = {};
    int bA = baddr(qb0 + 3, true, imgbase, hi);
    int bB = baddr(qb1 + 3, true, imgbase, hi);
    #pragma unroll
    for (int ks = 0; ks < 4; ++ks){
      bf16x8 a0 = *(const bf16x8*)(lw + col*64      + ks*16 + hi*8);
      bf16x8 a1 = *(const bf16x8*)(lw + (32+col)*64 + ks*16 + hi*8);
      bf16x8 b0 = *(const bf16x8*)(sm + (bA ^ (ks << 5)));
      bf16x8 b1 = *(const bf16x8*)(sm + (bB ^ (ks << 5)));
      c00 = MFMA32(a0, b0, c00); c01 = MFMA32(a0, b1, c01);
      c10 = MFMA32(a1, b0, c10); c11 = MFMA32(a1, b1, c11);
    }
    res_epi(c00, res00, 0, qb0, imgbase, hi, sm, lsp, lbp);
    res_epi(c01, res01, 0, qb1, imgbase, hi, sm, lsp, lbp);
    res_epi(c10, res10, 1, qb0, imgbase, hi, sm, lsp, lbp);
    res_epi(c11, res11, 1, qb1, imgbase, hi, sm, lsp, lbp);
  }

  // ---- value head (f32) ----
  float part0 = 0.f, part1 = 0.f;
  #pragma unroll
  for (int rg = 0; rg < 4; ++rg){
    #pragma unroll
    for (int eh = 0; eh < 2; ++eh){
      unsigned pA0 = res00[rg*2+eh], pA1 = res01[rg*2+eh];
      unsigned pB0 = res10[rg*2+eh], pB1 = res11[rg*2+eh];
      int ob = rg*8 + hi*4 + eh*2;
      float w0 = vconv_w[ob],      w1 = vconv_w[ob+1];
      float w2 = vconv_w[32+ob],   w3 = vconv_w[32+ob+1];
      part0 += bf2f((unsigned short)(pA0 & 0xffffu))*w0 + bf2f((unsigned short)(pA0 >> 16))*w1
             + bf2f((unsigned short)(pB0 & 0xffffu))*w2 + bf2f((unsigned short)(pB0 >> 16))*w3;
      part1 += bf2f((unsigned short)(pA1 & 0xffffu))*w0 + bf2f((unsigned short)(pA1 >> 16))*w1
             + bf2f((unsigned short)(pB1 & 0xffffu))*w2 + bf2f((unsigned short)(pB1 >> 16))*w3;
    }
  }
  part0 += __shfl_xor(part0, 32);
  part1 += __shfl_xor(part1, 32);
  float vs = v_s[0], vb = v_b[0];
  float vv0 = vs*part0 + vb; vv0 = vv0 > 0.f ? vv0 : 0.f;
  float vv1 = vs*part1 + vb; vv1 = vv1 > 0.f ? vv1 : 0.f;
  float* vbuf = (float*)(sm + xinbase);
  vbuf[p0]  = vv0;
  vbuf[p1c] = vv1;

  float hidv[4];
  #pragma unroll
  for (int it = 0; it < 4; ++it){
    int jj = it*64 + lane;
    float a = vfc1_b[jj];
    for (int k = 0; k < 64; k += 4){
      float4v vv = *(const float4v*)(vbuf + k);
      a += vfc1_w[jj*64+k]*vv[0] + vfc1_w[jj*64+k+1]*vv[1]
         + vfc1_w[jj*64+k+2]*vv[2] + vfc1_w[jj*64+k+3]*vv[3];
    }
    hidv[it] = a > 0.f ? a : 0.f;
  }
  float tot = 0.f;
  #pragma unroll
  for (int it = 0; it < 4; ++it) tot += hidv[it]*vfc2_w[it*64 + lane];
  #pragma unroll
  for (int off = 32; off; off >>= 1) tot += __shfl_xor(tot, off);
  if (lane == 0) value_out[img] = tanhf(tot + vfc2_b[0]);
}

// ======================= gather / piece head =======================
__global__ __launch_bounds__(256) void gather_k(const unsigned short* __restrict__ act0,
                                                unsigned short* __restrict__ pvec,
                                                float* __restrict__ pid_out){
  int lane = threadIdx.x & 63, wave = threadIdx.x >> 6;
  int img = blockIdx.x*4 + wave;
  const unsigned short* arow = act0 + (size_t)img*4096;
  int myid = (int)bf2f(arow[lane*64 + 63]);
  int mypos = 0, mypres = 0;
  for (int p = 0; p < 32; ++p){
    unsigned long long m = __ballot(myid == (p+1));
    if (lane == p){ mypres = (m != 0ull); mypos = mypres ? (__ffsll(m) - 1) : 0; }
  }
  if (lane < 32){
    float v = mypres ? (float)(lane+1) : 0.f;
    #pragma unroll
    for (int s = 0; s < 8; ++s) pid_out[(size_t)img*256 + s*32 + lane] = v;
  }
  for (int p = 0; p < 32; ++p){
    int q  = __shfl(mypos, p);
    int pr = __shfl(mypres, p);
    unsigned short v = pr ? arow[q*64 + lane] : (unsigned short)0;
    pvec[(size_t)img*2048 + p*64 + lane] = v;
  }
}

// ======================= policy head GEMMs =======================
__global__ __launch_bounds__(256) void fc1_k(const unsigned short* __restrict__ pvec,
                                             const unsigned short* __restrict__ w,
                                             const float* __restrict__ bias,
                                             unsigned short* __restrict__ hid){
  int lane = threadIdx.x & 63, wave = threadIdx.x >> 6;
  int col = lane & 31, hi = lane >> 5;
  int wm = wave >> 1, wn = wave & 1;
  int m0 = blockIdx.x*128 + wm*64;
  int n0 = blockIdx.y*128 + wn*64;
  f32x16 a00 = {}, a01 = {}, a10 = {}, a11 = {};
  for (int k = 0; k < 2048; k += 16){
    bf16x8 A0 = *(const bf16x8*)(pvec + (size_t)(m0+col)*2048    + k + hi*8);
    bf16x8 A1 = *(const bf16x8*)(pvec + (size_t)(m0+32+col)*2048 + k + hi*8);
    bf16x8 B0 = *(const bf16x8*)(w + (size_t)(n0+col)*2048    + k + hi*8);
    bf16x8 B1 = *(const bf16x8*)(w + (size_t)(n0+32+col)*2048 + k + hi*8);
    a00 = MFMA32(A0, B0, a00); a01 = MFMA32(A0, B1, a01);
    a10 = MFMA32(A1, B0, a10); a11 = MFMA32(A1, B1, a11);
  }
  #pragma unroll
  for (int mt = 0; mt < 2; ++mt)
    #pragma unroll
    for (int nt = 0; nt < 2; ++nt){
      const f32x16& acc = mt == 0 ? (nt == 0 ? a00 : a01) : (nt == 0 ? a10 : a11);
      int jcol = n0 + nt*32 + col;
      float bj = bias[jcol];
      #pragma unroll
      for (int rg = 0; rg < 4; ++rg)
        #pragma unroll
        for (int e = 0; e < 4; ++e){
          int n = m0 + mt*32 + rg*8 + hi*4 + e;
          float v = acc[rg*4+e] + bj; v = v > 0.f ? v : 0.f;
          hid[(size_t)n*256 + jcol] = f2bf(v);
        }
    }
}

__global__ __launch_bounds__(256) void fc2_k(const unsigned short* __restrict__ hid,
                                             const unsigned short* __restrict__ w,
                                             const float* __restrict__ bias,
                                             float* __restrict__ pol){
  int lane = threadIdx.x & 63, wave = threadIdx.x >> 6;
  int col = lane & 31, hi = lane >> 5;
  int wm = wave >> 1, wn = wave & 1;
  int m0 = blockIdx.x*128 + wm*64;
  int n0 = blockIdx.y*128 + wn*64;
  f32x16 a00 = {}, a01 = {}, a10 = {}, a11 = {};
  for (int k = 0; k < 256; k += 16){
    bf16x8 A0 = *(const bf16x8*)(hid + (size_t)(m0+col)*256    + k + hi*8);
    bf16x8 A1 = *(const bf16x8*)(hid + (size_t)(m0+32+col)*256 + k + hi*8);
    bf16x8 B0 = *(const bf16x8*)(w + (size_t)(n0+col)*256    + k + hi*8);
    bf16x8 B1 = *(const bf16x8*)(w + (size_t)(n0+32+col)*256 + k + hi*8);
    a00 = MFMA32(A0, B0, a00); a01 = MFMA32(A0, B1, a01);
    a10 = MFMA32(A1, B0, a10); a11 = MFMA32(A1, B1, a11);
  }
  #pragma unroll
  for (int mt = 0; mt < 2; ++mt)
    #pragma unroll
    for (int nt = 0; nt < 2; ++nt){
      const f32x16& acc = mt == 0 ? (nt == 0 ? a00 : a01) : (nt == 0 ? a10 : a11);
      int jcol = n0 + nt*32 + col;
      if (jcol < 1700){
        float bj = bias[jcol];
        #pragma unroll
        for (int rg = 0; rg < 4; ++rg)
          #pragma unroll
          for (int e = 0; e < 4; ++e){
            int n = m0 + mt*32 + rg*8 + hi*4 + e;
            pol[(size_t)n*1700 + jcol] = acc[rg*4+e] + bj;
          }
      }
    }
}

// ======================= launch =======================
extern "C" void kernel_launch(void* const* d_in, const int* in_sizes, int n_in,
                              void* d_out, int out_size, void* d_ws, size_t ws_size,
                              hipStream_t stream){
  const float* x       = (const float*)d_in[0];
  const float* first_w = (const float*)d_in[1];
  const float* first_s = (const float*)d_in[2];
  const float* first_b = (const float*)d_in[3];
  const float* res_w   = (const float*)d_in[4];
  const float* res_s   = (const float*)d_in[5];
  const float* res_b   = (const float*)d_in[6];
  const float* last_w  = (const float*)d_in[7];
  const float* last_s  = (const float*)d_in[8];
  const float* last_b  = (const float*)d_in[9];
  const float* pfc1_w  = (const float*)d_in[10];
  const float* pfc1_b  = (const float*)d_in[11];
  const float* pfc2_w  = (const float*)d_in[12];
  const float* pfc2_b  = (const float*)d_in[13];
  const float* vconv_w = (const float*)d_in[14];
  const float* v_s     = (const float*)d_in[15];
  const float* v_b     = (const float*)d_in[16];
  const float* vfc1_w  = (const float*)d_in[17];
  const float* vfc1_b  = (const float*)d_in[18];
  const float* vfc2_w  = (const float*)d_in[19];
  const float* vfc2_b  = (const float*)d_in[20];
  unsigned short* ws = (unsigned short*)d_ws;
  float* out = (float*)d_out;

  prep_res_k <<<3136, 256, 0, stream>>>(res_w, ws);
  prep_misc_k<<<1024, 256, 0, stream>>>(first_w, last_w, pfc1_w, pfc2_w, ws);
  tower_k    <<<256, 256, 0, stream>>>(x, first_s, first_b, res_s, res_b, last_s, last_b,
                                       vconv_w, v_s, v_b, vfc1_w, vfc1_b, vfc2_w, vfc2_b,
                                       ws, ws + ACT0_OFF, out + VAL_OFF);
  gather_k   <<<256, 256, 0, stream>>>(ws + ACT0_OFF, ws + PV_OFF, out + PID_OFF);
  fc1_k      <<<dim3(8, 2), 256, 0, stream>>>(ws + PV_OFF, ws + P1_OFF, pfc1_b, ws + HID_OFF);
  fc2_k      <<<dim3(8, 14), 256, 0, stream>>>(ws + HID_OFF, ws + P2_OFF, pfc2_b, out);
}